// Round 6
// baseline (718.347 us; speedup 1.0000x reference)
//
#include <hip/hip_runtime.h>
#include <hip/hip_bf16.h>
#include <math.h>

// Problem constants
#define NF 172
#define TF_ 100
#define EF 172
#define EDIM 272      // query/embed dim
#define KD 444        // kv dim
#define NNB 20        // neighbors
#define HD 136        // head dim
#define OUT_D 172

typedef __attribute__((ext_vector_type(4))) float f32x4;
typedef __attribute__((ext_vector_type(8))) __bf16 bf16x8;
typedef __attribute__((ext_vector_type(4))) __bf16 bf16x4;

// ---------------------------------------------------------------------------
// K0: sniff mask dtype. flag: 0 = int32, 1 = uint8, 2 = float32
// ---------------------------------------------------------------------------
__global__ void sniff_k(const unsigned char* __restrict__ m, int* __restrict__ flag) {
    __shared__ int c1, c2;
    if (threadIdx.x == 0) { c1 = 0; c2 = 0; }
    __syncthreads();
    for (int k = 0; k < 4; ++k) {
        int p = threadIdx.x * 4 + k;
        unsigned char v = m[p];
        if ((p & 3) != 0 && v)          atomicOr(&c1, 1);
        if ((p & 3) == 3 && v == 0x3f)  atomicOr(&c2, 1);
    }
    __syncthreads();
    if (threadIdx.x == 0) flag[0] = c2 ? 2 : (c1 ? 1 : 0);
}

// ---------------------------------------------------------------------------
// P: prep kernel — fold weight chains (all fp32, tiny).
//   GT[j=h*444+jj][k] = sum_c q_w[(h*136+c)*272+k] * k_w[(h*136+c)*444+jj]
//   gb[j]             = sum_c q_b[h*136+c]         * k_w[(h*136+c)*444+jj]
//   MT[j][r=h*444+d]  = sum_c v_w[(h*136+c)*444+d] * out_w[j*272 + h*136+c]
//   mb[j]             = out_b[j] + sum_e v_b[e]    * out_w[j*272+e]
// Grid: 888 (GT) + 272 (MT) + 4 (gb) + 2 (mb) = 1166 blocks x 256.
// ---------------------------------------------------------------------------
__global__ __launch_bounds__(256) void prep_k(
    const float* __restrict__ q_w, const float* __restrict__ k_w,
    const float* __restrict__ v_w, const float* __restrict__ q_b,
    const float* __restrict__ v_b, const float* __restrict__ out_w,
    const float* __restrict__ out_b,
    float* __restrict__ GT, float* __restrict__ gb,
    float* __restrict__ MT, float* __restrict__ mb)
{
    const int blk = blockIdx.x;
    const int tid = threadIdx.x;
    if (blk < 888) {
        const int j = blk, h = j / 444, jj = j - h * 444;
        for (int k = tid; k < 272; k += 256) {
            float acc = 0.f;
#pragma unroll 4
            for (int c = 0; c < 136; ++c)
                acc += q_w[(size_t)(h * 136 + c) * 272 + k] *
                       k_w[(size_t)(h * 136 + c) * 444 + jj];
            GT[(size_t)j * 272 + k] = acc;
        }
    } else if (blk < 888 + 272) {
        const int j = blk - 888;
        for (int r = tid; r < 888; r += 256) {
            const int h = r / 444, d = r - h * 444;
            float acc = 0.f;
#pragma unroll 4
            for (int c = 0; c < 136; ++c)
                acc += v_w[(size_t)(h * 136 + c) * 444 + d] *
                       out_w[(size_t)j * 272 + h * 136 + c];
            MT[(size_t)j * 888 + r] = acc;
        }
    } else if (blk < 888 + 272 + 4) {
        const int j = (blk - 888 - 272) * 256 + tid;
        if (j < 888) {
            const int h = j / 444, jj = j - h * 444;
            float acc = 0.f;
#pragma unroll 4
            for (int c = 0; c < 136; ++c)
                acc += q_b[h * 136 + c] * k_w[(size_t)(h * 136 + c) * 444 + jj];
            gb[j] = acc;
        }
    } else {
        const int j = (blk - 888 - 272 - 4) * 256 + tid;
        if (j < 272) {
            float acc = out_b[j];
#pragma unroll 4
            for (int e = 0; e < 272; ++e)
                acc += v_b[e] * out_w[(size_t)j * 272 + e];
            mb[j] = acc;
        }
    }
}

// ---------------------------------------------------------------------------
// bf16-MFMA GEMM, double-buffered 2-phase (T3-min): one barrier per K-step,
// next tile's global loads issued before the MFMA phase.
//   C[r,n] = act( sum_k A[r,k]*W[n,k] + bias[n] ) * live(r)
//   A fp32 = concat(A0[:,0:a0_cols], A1); W fp32 [N][K] row-major.
//   Tile 128x128, BK=32, 4 waves x (64x64 = 4x4 frags of 16x16x32).
//   Frag layouts m89-verified (round-3 validated).
// ---------------------------------------------------------------------------
#define BKP 40   // padded k-stride in LDS (bf16 elems)

__global__ __launch_bounds__(256) void gemm_mfma_k(
    const float* __restrict__ A0, int a0_cols, int a0_stride,
    const float* __restrict__ A1, int a1_stride,
    const float* __restrict__ W, int w_stride,
    const float* __restrict__ bias,
    const float* __restrict__ invalf,
    int relu,
    float* __restrict__ C, int c_stride,
    int N, int K)
{
    __shared__ __bf16 As[2][128][BKP];
    __shared__ __bf16 Bs[2][128][BKP];

    const int tid  = threadIdx.x;
    const int lane = tid & 63;
    const int wv   = tid >> 6;
    const int wr   = wv >> 1;
    const int wc   = wv & 1;
    const int lr   = lane & 15;
    const int lg   = lane >> 4;
    const int m0   = blockIdx.x * 128;
    const int n0   = blockIdx.y * 128;

    f32x4 acc[4][4];
#pragma unroll
    for (int i = 0; i < 4; ++i)
#pragma unroll
        for (int j = 0; j < 4; ++j) acc[i][j] = (f32x4)(0.f);

    const int srow = tid >> 1;         // 0..127
    const int sch0 = (tid & 1) * 4;    // chunk base
    const float4 z4 = make_float4(0.f, 0.f, 0.f, 0.f);
    float4 va[4], vb[4];

#define LOAD_T(k0base) do {                                                   \
    _Pragma("unroll")                                                         \
    for (int i_ = 0; i_ < 4; ++i_) {                                          \
        const int k_ = (k0base) + (sch0 + i_) * 4;                            \
        va[i_] = z4; vb[i_] = z4;                                             \
        if (k_ < K) {                                                         \
            const float* p_ = (k_ < a0_cols)                                  \
                ? (A0 + (size_t)(m0 + srow) * a0_stride + k_)                 \
                : (A1 + (size_t)(m0 + srow) * a1_stride + (k_ - a0_cols));    \
            va[i_] = *(const float4*)p_;                                      \
            if ((n0 + srow) < N)                                              \
                vb[i_] = *(const float4*)(W + (size_t)(n0 + srow) * w_stride + k_); \
        }                                                                     \
    } } while (0)

#define STORE_T(bufi) do {                                                    \
    _Pragma("unroll")                                                         \
    for (int i_ = 0; i_ < 4; ++i_) {                                          \
        bf16x4 ta_, tb_;                                                      \
        ta_[0] = (__bf16)va[i_].x; ta_[1] = (__bf16)va[i_].y;                 \
        ta_[2] = (__bf16)va[i_].z; ta_[3] = (__bf16)va[i_].w;                 \
        tb_[0] = (__bf16)vb[i_].x; tb_[1] = (__bf16)vb[i_].y;                 \
        tb_[2] = (__bf16)vb[i_].z; tb_[3] = (__bf16)vb[i_].w;                 \
        *(bf16x4*)&As[bufi][srow][(sch0 + i_) * 4] = ta_;                     \
        *(bf16x4*)&Bs[bufi][srow][(sch0 + i_) * 4] = tb_;                     \
    } } while (0)

    const int ktiles = (K + 31) / 32;
    LOAD_T(0);
    STORE_T(0);
    __syncthreads();

    int cur = 0;
    for (int t = 0; t < ktiles; ++t) {
        const int more = (t + 1 < ktiles);
        if (more) LOAD_T((t + 1) * 32);          // loads in flight across MFMA

        bf16x8 af[4], bfr[4];
#pragma unroll
        for (int f = 0; f < 4; ++f) {
            af[f]  = *(const bf16x8*)&As[cur][wr * 64 + f * 16 + lr][lg * 8];
            bfr[f] = *(const bf16x8*)&Bs[cur][wc * 64 + f * 16 + lr][lg * 8];
        }
#pragma unroll
        for (int fm = 0; fm < 4; ++fm)
#pragma unroll
            for (int fn = 0; fn < 4; ++fn)
                acc[fm][fn] = __builtin_amdgcn_mfma_f32_16x16x32_bf16(
                    af[fm], bfr[fn], acc[fm][fn], 0, 0, 0);

        if (more) STORE_T(cur ^ 1);              // write next buf (safe: last read ended at prev barrier)
        __syncthreads();
        cur ^= 1;
    }
#undef LOAD_T
#undef STORE_T

    // epilogue: D col=l&15, row=4*(l>>4)+reg (validated)
    float bv[4];
#pragma unroll
    for (int fn = 0; fn < 4; ++fn) {
        const int col = n0 + wc * 64 + fn * 16 + lr;
        bv[fn] = (bias && col < N) ? bias[col] : 0.f;
    }
#pragma unroll
    for (int fm = 0; fm < 4; ++fm) {
#pragma unroll
        for (int j = 0; j < 4; ++j) {
            const int row = m0 + wr * 64 + fm * 16 + lg * 4 + j;
            float zf = 1.f;
            if (invalf && invalf[row] != 0.f) zf = 0.f;
#pragma unroll
            for (int fn = 0; fn < 4; ++fn) {
                const int col = n0 + wc * 64 + fn * 16 + lr;
                if (col < N) {
                    float v = acc[fm][fn][j] + bv[fn];
                    if (relu) v = fmaxf(v, 0.f);
                    C[(size_t)row * c_stride + col] = v * zf;
                }
            }
        }
    }
}

// ---------------------------------------------------------------------------
// K3: attention, 2 waves per row, kv register-resident, deferred softmax.
//   Block 256 thr = 2 rows x 2 waves. Wave (row rw, half hf) owns neighbors
//   hf*10..hf*10+9, holds their kv column-slices in registers (kA/kB),
//   computes 20 independent pipelined butterflies (no exp in any chain),
//   exchanges scores via LDS, softmax redundantly per lane, weighted-FMA
//   from registers, partner-acc exchange via LDS. No kv re-read.
// ---------------------------------------------------------------------------
__device__ __forceinline__ float dot4(float4 a, float4 b) {
    return a.x * b.x + a.y * b.y + a.z * b.z + a.w * b.w;
}

__global__ __launch_bounds__(256) void attn_flash2_k(
    const float* __restrict__ nf, const float* __restrict__ ef,
    const float* __restrict__ ntf,
    const unsigned char* __restrict__ maskp,
    const int* __restrict__ mode_p,
    const float* __restrict__ qk,
    float* __restrict__ wkv,
    float* __restrict__ invalf,
    float* __restrict__ attnw)
{
    __shared__ float  sc_lds[2][2][NNB];
    __shared__ float4 acc_lds[2][4][64];

    const int tid  = threadIdx.x;
    const int lane = tid & 63;
    const int wv   = tid >> 6;
    const int rw   = wv >> 1;            // row within block
    const int hf   = wv & 1;             // neighbor half
    const int b    = blockIdx.x * 2 + rw;
    const int mode = mode_p[0];

    // ---- mask bits (lane<20) ----
    int mv = 0;
    if (lane < NNB) {
        if (mode == 0)      mv = ((const int*)maskp)[(size_t)b * NNB + lane] != 0;
        else if (mode == 1) mv = maskp[(size_t)b * NNB + lane] != 0;
        else                mv = ((const float*)maskp)[(size_t)b * NNB + lane] != 0.f;
    }
    unsigned long long bal = __ballot(lane < NNB && mv);
    const int inv = ((bal & 0xFFFFFULL) == 0xFFFFFULL);
    if (inv && lane == 0) mv = 0;        // force-unmask neighbor 0
    if (hf == 0 && lane == 0) invalf[b] = (float)inv;

    // ---- q fragments ----
    const float* qrow = qk + (size_t)b * 888;
    const float4 z4 = make_float4(0.f, 0.f, 0.f, 0.f);
    float4 q0a = *(const float4*)(qrow + lane * 4);
    float4 q1a = *(const float4*)(qrow + KD + lane * 4);
    float4 q0b = z4, q1b = z4;
    if (lane < 47) {
        q0b = *(const float4*)(qrow + (64 + lane) * 4);
        q1b = *(const float4*)(qrow + KD + (64 + lane) * 4);
    }

    // ---- kv load for this wave's 10 neighbors (register-resident) ----
    const size_t rbase = (size_t)b * NNB + hf * 10;
    const float* pA;
    if (lane < 43) pA = nf + rbase * NF + lane * 4;
    else           pA = ef + rbase * EF + (lane - 43) * 4;
    const float* pB;
    int strideB;
    if (lane < 22) { pB = ef  + rbase * EF  + (21 + lane) * 4; strideB = EF;  }
    else           { pB = ntf + rbase * TF_ + (lane - 22) * 4; strideB = TF_; }

    float4 kA[10], kB[10];
#pragma unroll
    for (int s = 0; s < 10; ++s) {
        kA[s] = *(const float4*)pA; pA += NF;
        kB[s] = z4;
        if (lane < 47) { kB[s] = *(const float4*)pB; }
        pB += strideB;
    }

    // ---- partial dots, then 20 independent butterflies ----
    float s0v[10], s1v[10];
#pragma unroll
    for (int s = 0; s < 10; ++s) {
        s0v[s] = dot4(q0a, kA[s]) + dot4(q0b, kB[s]);
        s1v[s] = dot4(q1a, kA[s]) + dot4(q1b, kB[s]);
    }
#pragma unroll
    for (int off = 32; off; off >>= 1) {
#pragma unroll
        for (int s = 0; s < 10; ++s) {
            s0v[s] += __shfl_xor(s0v[s], off);
            s1v[s] += __shfl_xor(s1v[s], off);
        }
    }

    // ---- mask + scale, publish scores ----
    const float scal = 0.08574929257125441f;  // 1/sqrt(136)
#pragma unroll
    for (int s = 0; s < 10; ++s) {
        const int g = hf * 10 + s;
        const int mn = __shfl(mv, g);
        s0v[s] = mn ? -1e30f : s0v[s] * scal;
        s1v[s] = mn ? -1e30f : s1v[s] * scal;
        if (lane == s) { sc_lds[rw][0][g] = s0v[s]; sc_lds[rw][1][g] = s1v[s]; }
    }
    __syncthreads();

    // ---- softmax stats over all 20 (redundant per lane; LDS broadcasts) ----
    float m0 = -3.4e38f, m1 = -3.4e38f;
#pragma unroll
    for (int g = 0; g < NNB; ++g) {
        m0 = fmaxf(m0, sc_lds[rw][0][g]);
        m1 = fmaxf(m1, sc_lds[rw][1][g]);
    }
    float sum0 = 0.f, sum1 = 0.f;
#pragma unroll
    for (int g = 0; g < NNB; ++g) {
        sum0 += expf(sc_lds[rw][0][g] - m0);
        sum1 += expf(sc_lds[rw][1][g] - m1);
    }
    const float r0 = 1.f / sum0;
    const float r1 = 1.f / sum1;

    // ---- weighted accumulation from registers ----
    float4 a0a = z4, a0b = z4, a1a = z4, a1b = z4;
#pragma unroll
    for (int s = 0; s < 10; ++s) {
        const float w0 = expf(s0v[s] - m0) * r0;
        const float w1 = expf(s1v[s] - m1) * r1;
        a0a.x += w0 * kA[s].x; a0a.y += w0 * kA[s].y; a0a.z += w0 * kA[s].z; a0a.w += w0 * kA[s].w;
        a0b.x += w0 * kB[s].x; a0b.y += w0 * kB[s].y; a0b.z += w0 * kB[s].z; a0b.w += w0 * kB[s].w;
        a1a.x += w1 * kA[s].x; a1a.y += w1 * kA[s].y; a1a.z += w1 * kA[s].z; a1a.w += w1 * kA[s].w;
        a1b.x += w1 * kB[s].x; a1b.y += w1 * kB[s].y; a1b.z += w1 * kB[s].z; a1b.w += w1 * kB[s].w;
    }

    // ---- partner exchange + store ----
    if (hf == 1) {
        acc_lds[rw][0][lane] = a0a;
        acc_lds[rw][1][lane] = a0b;
        acc_lds[rw][2][lane] = a1a;
        acc_lds[rw][3][lane] = a1b;
    }
    __syncthreads();
    if (hf == 0) {
        float4 p0a = acc_lds[rw][0][lane], p0b = acc_lds[rw][1][lane];
        float4 p1a = acc_lds[rw][2][lane], p1b = acc_lds[rw][3][lane];
        a0a.x += p0a.x; a0a.y += p0a.y; a0a.z += p0a.z; a0a.w += p0a.w;
        a0b.x += p0b.x; a0b.y += p0b.y; a0b.z += p0b.z; a0b.w += p0b.w;
        a1a.x += p1a.x; a1a.y += p1a.y; a1a.z += p1a.z; a1a.w += p1a.w;
        a1b.x += p1b.x; a1b.y += p1b.y; a1b.z += p1b.z; a1b.w += p1b.w;

        float* wrow = wkv + (size_t)b * 888;
        *(float4*)(wrow + lane * 4)      = a0a;
        *(float4*)(wrow + KD + lane * 4) = a1a;
        if (lane < 47) {
            *(float4*)(wrow + (64 + lane) * 4)      = a0b;
            *(float4*)(wrow + KD + (64 + lane) * 4) = a1b;
        }
        // attn_weights (mean over heads) from published scores
#pragma unroll
        for (int g = 0; g < NNB; ++g) {
            if (lane == g)
                attnw[(size_t)b * NNB + g] =
                    0.5f * (expf(sc_lds[rw][0][g] - m0) * r0 +
                            expf(sc_lds[rw][1][g] - m1) * r1);
        }
    }
}

// ---------------------------------------------------------------------------
extern "C" void kernel_launch(void* const* d_in, const int* in_sizes, int n_in,
                              void* d_out, int out_size, void* d_ws, size_t ws_size,
                              hipStream_t stream) {
    const float* src_node = (const float*)d_in[0];
    const float* src_time = (const float*)d_in[1];
    const float* nfp      = (const float*)d_in[2];
    const float* ntfp     = (const float*)d_in[3];  // neighbor_time
    const float* efp      = (const float*)d_in[4];  // edge
    const unsigned char* maskp = (const unsigned char*)d_in[5];
    const float* q_w   = (const float*)d_in[6];
    const float* k_w   = (const float*)d_in[7];
    const float* v_w   = (const float*)d_in[8];
    const float* q_b   = (const float*)d_in[9];
    // d_in[10] = k_b: no effect on outputs (uniform shift under softmax)
    const float* v_b   = (const float*)d_in[11];
    const float* out_w = (const float*)d_in[12];
    const float* out_b = (const float*)d_in[13];
    const float* m1_w  = (const float*)d_in[14];
    const float* m1_b  = (const float*)d_in[15];
    const float* m2_w  = (const float*)d_in[16];
    const float* m2_b  = (const float*)d_in[17];

    const int B = in_sizes[0] / NF;   // 32768

    // ws layout (aliasing, stream-ordered safe; ~154 MB like round-2's known-good):
    //  flag[16] | qkb [B,888] (qk -> wkv -> hidden) | invb [B] | aob [B,272]
    //  | GT [888x272] | gb [888] | MT [272x888] | mb [272]
    float* ws   = (float*)d_ws;
    int*   flag = (int*)d_ws;
    float* qkb  = ws + 16;
    float* invb = qkb + (size_t)B * 888;
    float* aob  = invb + B;
    float* GT   = aob + (size_t)B * 272;
    float* gb   = GT + 888 * 272;
    float* MT   = gb + 888;
    float* mb   = MT + 272 * 888;
    float* hidb = qkb;                           // reuse qkb after GEMM2 consumed it
    float* outp  = (float*)d_out;                // [B,172]
    float* attnw = outp + (size_t)B * OUT_D;     // [B,20]

    const int gm = B / 128;   // 256

    sniff_k<<<1, 256, 0, stream>>>(maskp, flag);
    prep_k<<<1166, 256, 0, stream>>>(q_w, k_w, v_w, q_b, v_b, out_w, out_b,
                                     GT, gb, MT, mb);

    // GEMM1: qk[B,888] = concat(src_node, src_time) @ GT^T + gb   (K=272)
    gemm_mfma_k<<<dim3(gm, 7), 256, 0, stream>>>(
        src_node, NF, NF, src_time, TF_,
        GT, 272, gb, nullptr, 0, qkb, 888, 888, 272);

    // K3: attention (wkv aliases qk; same-row read-before-write, barrier-ordered)
    attn_flash2_k<<<B / 2, 256, 0, stream>>>(nfp, efp, ntfp, maskp, flag,
                                             qkb, qkb, invb, attnw);

    // GEMM2: attn_out[B,272] = wkv[B,888] @ MT^T + mb, zeroed where invalid
    gemm_mfma_k<<<dim3(gm, 3), 256, 0, stream>>>(
        qkb, 888, 888, nullptr, 0,
        MT, 888, mb, invb, 0, aob, 272, 272, 888);

    // K7: hidden = relu(concat(attn_out, src_node) @ m1_w.T + m1_b)  (-> qkb region)
    gemm_mfma_k<<<dim3(gm, 2), 256, 0, stream>>>(
        aob, EDIM, EDIM, src_node, NF,
        m1_w, KD, m1_b, nullptr, 1, hidb, OUT_D, OUT_D, KD);

    // K8: out = hidden @ m2_w.T + m2_b
    gemm_mfma_k<<<dim3(gm, 2), 256, 0, stream>>>(
        hidb, OUT_D, OUT_D, nullptr, 0,
        m2_w, OUT_D, m2_b, nullptr, 0, outp, OUT_D, OUT_D, OUT_D);
}

// Round 7
// 665.263 us; speedup vs baseline: 1.0798x; 1.0798x over previous
//
#include <hip/hip_runtime.h>
#include <hip/hip_bf16.h>
#include <math.h>

// Problem constants
#define NF 172
#define TF_ 100
#define EF 172
#define EDIM 272      // query/embed dim
#define KD 444        // kv dim
#define NNB 20        // neighbors
#define HD 136        // head dim
#define OUT_D 172

typedef __attribute__((ext_vector_type(4))) float f32x4;
typedef __attribute__((ext_vector_type(8))) __bf16 bf16x8;
typedef __attribute__((ext_vector_type(4))) __bf16 bf16x4;

// log2(e) / sqrt(136): softmax base-2 rescale (exact softmax equivalence)
#define SC2 0.12371009f

// ---------------------------------------------------------------------------
// K0: sniff mask dtype. flag: 0 = int32, 1 = uint8, 2 = float32
// ---------------------------------------------------------------------------
__global__ void sniff_k(const unsigned char* __restrict__ m, int* __restrict__ flag) {
    __shared__ int c1, c2;
    if (threadIdx.x == 0) { c1 = 0; c2 = 0; }
    __syncthreads();
    for (int k = 0; k < 4; ++k) {
        int p = threadIdx.x * 4 + k;
        unsigned char v = m[p];
        if ((p & 3) != 0 && v)          atomicOr(&c1, 1);
        if ((p & 3) == 3 && v == 0x3f)  atomicOr(&c2, 1);
    }
    __syncthreads();
    if (threadIdx.x == 0) flag[0] = c2 ? 2 : (c1 ? 1 : 0);
}

// ---------------------------------------------------------------------------
// prep1: GT/gb (q∘k fold), OW2 = m1_wA @ out_w, mb = out_b + out_w@v_b
// blocks: [0,888) GT | [888,1060) OW2 | [1060,1064) gb | 1064 mb
// ---------------------------------------------------------------------------
__global__ __launch_bounds__(256) void prep1_k(
    const float* __restrict__ q_w, const float* __restrict__ k_w,
    const float* __restrict__ q_b, const float* __restrict__ v_b,
    const float* __restrict__ out_w, const float* __restrict__ out_b,
    const float* __restrict__ m1_w,
    float* __restrict__ GT, float* __restrict__ gb,
    float* __restrict__ OW2, float* __restrict__ mb)
{
    const int blk = blockIdx.x;
    const int tid = threadIdx.x;
    if (blk < 888) {
        const int j = blk, h = j / 444, jj = j - h * 444;
        for (int k = tid; k < 272; k += 256) {
            float acc = 0.f;
#pragma unroll 4
            for (int c = 0; c < 136; ++c)
                acc += q_w[(size_t)(h * 136 + c) * 272 + k] *
                       k_w[(size_t)(h * 136 + c) * 444 + jj];
            GT[(size_t)j * 272 + k] = acc;
        }
    } else if (blk < 1060) {
        const int j = blk - 888;           // 0..171
        for (int k = tid; k < 272; k += 256) {
            float acc = 0.f;
#pragma unroll 4
            for (int e = 0; e < 272; ++e)
                acc += m1_w[(size_t)j * 444 + e] * out_w[(size_t)e * 272 + k];
            OW2[(size_t)j * 272 + k] = acc;
        }
    } else if (blk < 1064) {
        const int j = (blk - 1060) * 256 + tid;
        if (j < 888) {
            const int h = j / 444, jj = j - h * 444;
            float acc = 0.f;
#pragma unroll 4
            for (int c = 0; c < 136; ++c)
                acc += q_b[h * 136 + c] * k_w[(size_t)(h * 136 + c) * 444 + jj];
            gb[j] = acc;
        }
    } else {
        for (int j = tid; j < 272; j += 256) {
            float acc = out_b[j];
#pragma unroll 4
            for (int e = 0; e < 272; ++e)
                acc += v_b[e] * out_w[(size_t)j * 272 + e];
            mb[j] = acc;
        }
    }
}

// ---------------------------------------------------------------------------
// prep2: W2[j][0:888] = (m1_wA@MT)[j] via OW2;  W2[j][888:1060] = m1_wB[j];
//        bias_v[j] = m1_b[j] + m1_wA[j]@mb
// blocks: [0,172) per-j | 172 bias_v
// ---------------------------------------------------------------------------
__global__ __launch_bounds__(256) void prep2_k(
    const float* __restrict__ v_w, const float* __restrict__ m1_w,
    const float* __restrict__ m1_b,
    const float* __restrict__ OW2, const float* __restrict__ mb,
    float* __restrict__ W2, float* __restrict__ bias_v)
{
    const int blk = blockIdx.x;
    const int tid = threadIdx.x;
    if (blk < 172) {
        const int j = blk;
        for (int r = tid; r < 888; r += 256) {
            const int h = (r >= 444);
            const int d = r - h * 444;
            float acc = 0.f;
#pragma unroll 4
            for (int c = 0; c < 136; ++c)
                acc += v_w[(size_t)(h * 136 + c) * 444 + d] *
                       OW2[(size_t)j * 272 + h * 136 + c];
            W2[(size_t)j * 1060 + r] = acc;
        }
        for (int k = tid; k < 172; k += 256)
            W2[(size_t)j * 1060 + 888 + k] = m1_w[(size_t)j * 444 + 272 + k];
    } else {
        for (int j = tid; j < 172; j += 256) {
            float acc = m1_b[j];
#pragma unroll 4
            for (int e = 0; e < 272; ++e)
                acc += m1_w[(size_t)j * 444 + e] * mb[e];
            bias_v[j] = acc;
        }
    }
}

// ---------------------------------------------------------------------------
// bf16-MFMA GEMM, double-buffered 2-phase + XCD-chunked swizzle (grid%8==0).
//   C[r,n] = act( sum_k A[r,k]*W[n,k] + bias_sel[n] )
//   bias_sel = (invalf[r] != 0 && bias_inv) ? bias_inv : bias.
//   A fp32 = concat(A0[:,0:a0_cols], A1); W fp32 [N][K] row-major.
// ---------------------------------------------------------------------------
#define BKP 40   // padded k-stride in LDS (bf16 elems)

__global__ __launch_bounds__(256) void gemm_mfma_k(
    const float* __restrict__ A0, int a0_cols, int a0_stride,
    const float* __restrict__ A1, int a1_stride,
    const float* __restrict__ W, int w_stride,
    const float* __restrict__ bias,
    const float* __restrict__ bias_inv,
    const float* __restrict__ invalf,
    int relu,
    float* __restrict__ C, int c_stride,
    int N, int K)
{
    __shared__ __bf16 As[2][128][BKP];
    __shared__ __bf16 Bs[2][128][BKP];

    const int tid  = threadIdx.x;
    const int lane = tid & 63;
    const int wv   = tid >> 6;
    const int wr   = wv >> 1;
    const int wc   = wv & 1;
    const int lr   = lane & 15;
    const int lg   = lane >> 4;

    // XCD-chunked bijective swizzle (nwg % 8 == 0), y-fast within chunk:
    // contiguous A-panels stay on one XCD; W panels L2-resident.
    const int nt   = gridDim.y;
    const int nwg  = gridDim.x * nt;
    const int lid  = blockIdx.x + blockIdx.y * gridDim.x;
    const int swz  = (lid & 7) * (nwg >> 3) + (lid >> 3);
    const int xt   = swz / nt;
    const int yt   = swz - xt * nt;
    const int m0   = xt * 128;
    const int n0   = yt * 128;

    f32x4 acc[4][4];
#pragma unroll
    for (int i = 0; i < 4; ++i)
#pragma unroll
        for (int j = 0; j < 4; ++j) acc[i][j] = (f32x4)(0.f);

    const int srow = tid >> 1;         // 0..127
    const int sch0 = (tid & 1) * 4;    // chunk base
    const float4 z4 = make_float4(0.f, 0.f, 0.f, 0.f);
    float4 va[4], vb[4];

#define LOAD_T(k0base) do {                                                   \
    _Pragma("unroll")                                                         \
    for (int i_ = 0; i_ < 4; ++i_) {                                          \
        const int k_ = (k0base) + (sch0 + i_) * 4;                            \
        va[i_] = z4; vb[i_] = z4;                                             \
        if (k_ < K) {                                                         \
            const float* p_ = (k_ < a0_cols)                                  \
                ? (A0 + (size_t)(m0 + srow) * a0_stride + k_)                 \
                : (A1 + (size_t)(m0 + srow) * a1_stride + (k_ - a0_cols));    \
            va[i_] = *(const float4*)p_;                                      \
            if ((n0 + srow) < N)                                              \
                vb[i_] = *(const float4*)(W + (size_t)(n0 + srow) * w_stride + k_); \
        }                                                                     \
    } } while (0)

#define STORE_T(bufi) do {                                                    \
    _Pragma("unroll")                                                         \
    for (int i_ = 0; i_ < 4; ++i_) {                                          \
        bf16x4 ta_, tb_;                                                      \
        ta_[0] = (__bf16)va[i_].x; ta_[1] = (__bf16)va[i_].y;                 \
        ta_[2] = (__bf16)va[i_].z; ta_[3] = (__bf16)va[i_].w;                 \
        tb_[0] = (__bf16)vb[i_].x; tb_[1] = (__bf16)vb[i_].y;                 \
        tb_[2] = (__bf16)vb[i_].z; tb_[3] = (__bf16)vb[i_].w;                 \
        *(bf16x4*)&As[bufi][srow][(sch0 + i_) * 4] = ta_;                     \
        *(bf16x4*)&Bs[bufi][srow][(sch0 + i_) * 4] = tb_;                     \
    } } while (0)

    const int ktiles = (K + 31) / 32;
    LOAD_T(0);
    STORE_T(0);
    __syncthreads();

    int cur = 0;
    for (int t = 0; t < ktiles; ++t) {
        const int more = (t + 1 < ktiles);
        if (more) LOAD_T((t + 1) * 32);          // loads in flight across MFMA

        bf16x8 af[4], bfr[4];
#pragma unroll
        for (int f = 0; f < 4; ++f) {
            af[f]  = *(const bf16x8*)&As[cur][wr * 64 + f * 16 + lr][lg * 8];
            bfr[f] = *(const bf16x8*)&Bs[cur][wc * 64 + f * 16 + lr][lg * 8];
        }
#pragma unroll
        for (int fm = 0; fm < 4; ++fm)
#pragma unroll
            for (int fn = 0; fn < 4; ++fn)
                acc[fm][fn] = __builtin_amdgcn_mfma_f32_16x16x32_bf16(
                    af[fm], bfr[fn], acc[fm][fn], 0, 0, 0);

        if (more) STORE_T(cur ^ 1);
        __syncthreads();
        cur ^= 1;
    }
#undef LOAD_T
#undef STORE_T

    // epilogue: D col=l&15, row=4*(l>>4)+reg; per-row bias select
    float bv[4], bvi[4];
#pragma unroll
    for (int fn = 0; fn < 4; ++fn) {
        const int col = n0 + wc * 64 + fn * 16 + lr;
        bv[fn]  = (bias && col < N) ? bias[col] : 0.f;
        bvi[fn] = (bias_inv && col < N) ? bias_inv[col] : bv[fn];
    }
#pragma unroll
    for (int fm = 0; fm < 4; ++fm) {
#pragma unroll
        for (int j = 0; j < 4; ++j) {
            const int row = m0 + wr * 64 + fm * 16 + lg * 4 + j;
            const bool bad = invalf && invalf[row] != 0.f;
#pragma unroll
            for (int fn = 0; fn < 4; ++fn) {
                const int col = n0 + wc * 64 + fn * 16 + lr;
                if (col < N) {
                    float v = acc[fm][fn][j] + (bad ? bvi[fn] : bv[fn]);
                    if (relu) v = fmaxf(v, 0.f);
                    C[(size_t)row * c_stride + col] = v;
                }
            }
        }
    }
}

// ---------------------------------------------------------------------------
// K3: attention v3. ONE ROW PER BLOCK, 4 waves x 5 neighbors, kv in regs.
//   Reduction: 4 DPP row_ror adds (VALU) + 2 shfl_xor (DS) per value.
//   Softmax: per-wave local max/sum exchanged via 12 LDS floats (no
//   redundant 40-deep loops). exp2f with log2e folded into scale.
//   Writes wkv = 0 for invalid rows (enables bias-select GEMM fold).
// ---------------------------------------------------------------------------
__device__ __forceinline__ float dot4(float4 a, float4 b) {
    return a.x * b.x + a.y * b.y + a.z * b.z + a.w * b.w;
}

__device__ __forceinline__ float wave_allsum(float x) {
    int t;
    t = __builtin_amdgcn_update_dpp(0, __float_as_int(x), 0x128, 0xf, 0xf, true); // row_ror:8
    x += __int_as_float(t);
    t = __builtin_amdgcn_update_dpp(0, __float_as_int(x), 0x124, 0xf, 0xf, true); // row_ror:4
    x += __int_as_float(t);
    t = __builtin_amdgcn_update_dpp(0, __float_as_int(x), 0x122, 0xf, 0xf, true); // row_ror:2
    x += __int_as_float(t);
    t = __builtin_amdgcn_update_dpp(0, __float_as_int(x), 0x121, 0xf, 0xf, true); // row_ror:1
    x += __int_as_float(t);
    x += __shfl_xor(x, 16);
    x += __shfl_xor(x, 32);
    return x;
}

__global__ __launch_bounds__(256) void attn_flash3_k(
    const float* __restrict__ nf, const float* __restrict__ ef,
    const float* __restrict__ ntf,
    const unsigned char* __restrict__ maskp,
    const int* __restrict__ mode_p,
    const float* __restrict__ qk,
    float* __restrict__ wkv,
    float* __restrict__ invalf,
    float* __restrict__ attnw)
{
    __shared__ float  sc[2][NNB];
    __shared__ float  lmax[4][2], lsum[4][2];
    __shared__ float4 accx[3][4][64];

    const int tid  = threadIdx.x;
    const int lane = tid & 63;
    const int w    = tid >> 6;         // wave 0..3, owns neighbors 5w..5w+4
    const int b    = blockIdx.x;
    const int mode = mode_p[0];

    // ---- mask via ballot bits (no shfl) ----
    int mv = 0;
    if (lane < NNB) {
        if (mode == 0)      mv = ((const int*)maskp)[(size_t)b * NNB + lane] != 0;
        else if (mode == 1) mv = maskp[(size_t)b * NNB + lane] != 0;
        else                mv = ((const float*)maskp)[(size_t)b * NNB + lane] != 0.f;
    }
    unsigned long long bal = __ballot(lane < NNB && mv) & 0xFFFFFULL;
    const int inv = (bal == 0xFFFFFULL);
    if (inv) bal &= ~1ULL;             // force-unmask neighbor 0
    if (w == 0 && lane == 0) invalf[b] = (float)inv;

    // ---- q fragments ----
    const float* qrow = qk + (size_t)b * 888;
    const float4 z4 = make_float4(0.f, 0.f, 0.f, 0.f);
    float4 q0a = *(const float4*)(qrow + lane * 4);
    float4 q1a = *(const float4*)(qrow + KD + lane * 4);
    float4 q0b = z4, q1b = z4;
    if (lane < 47) {
        q0b = *(const float4*)(qrow + (64 + lane) * 4);
        q1b = *(const float4*)(qrow + KD + (64 + lane) * 4);
    }

    // ---- kv (5 neighbors, register-resident) ----
    const size_t rbase = (size_t)b * NNB + w * 5;
    const float* pA;
    if (lane < 43) pA = nf + rbase * NF + lane * 4;
    else           pA = ef + rbase * EF + (lane - 43) * 4;
    const float* pB;
    int strideB;
    if (lane < 22) { pB = ef  + rbase * EF  + (21 + lane) * 4; strideB = EF;  }
    else           { pB = ntf + rbase * TF_ + (lane - 22) * 4; strideB = TF_; }

    float4 kA[5], kB[5];
#pragma unroll
    for (int s = 0; s < 5; ++s) {
        kA[s] = *(const float4*)pA; pA += NF;
        kB[s] = z4;
        if (lane < 47) kB[s] = *(const float4*)pB;
        pB += strideB;
    }

    // ---- dots + DPP reduce; scale + mask ----
    float s0[5], s1[5];
#pragma unroll
    for (int s = 0; s < 5; ++s) {
        s0[s] = wave_allsum(dot4(q0a, kA[s]) + dot4(q0b, kB[s]));
        s1[s] = wave_allsum(dot4(q1a, kA[s]) + dot4(q1b, kB[s]));
    }
#pragma unroll
    for (int s = 0; s < 5; ++s) {
        const int g = w * 5 + s;
        const int mn = (int)((bal >> g) & 1ULL);
        s0[s] = mn ? -1e30f : s0[s] * SC2;
        s1[s] = mn ? -1e30f : s1[s] * SC2;
        if (lane == s) { sc[0][g] = s0[s]; sc[1][g] = s1[s]; }
    }

    // ---- local max publish ----
    float lm0 = s0[0], lm1 = s1[0];
#pragma unroll
    for (int s = 1; s < 5; ++s) { lm0 = fmaxf(lm0, s0[s]); lm1 = fmaxf(lm1, s1[s]); }
    if (lane == 0) { lmax[w][0] = lm0; lmax[w][1] = lm1; }
    __syncthreads();                                   // B1

    const float m0 = fmaxf(fmaxf(lmax[0][0], lmax[1][0]), fmaxf(lmax[2][0], lmax[3][0]));
    const float m1 = fmaxf(fmaxf(lmax[0][1], lmax[1][1]), fmaxf(lmax[2][1], lmax[3][1]));

    // ---- own weights + local sums (base-2 exp, single TRANS instr) ----
    float u0[5], u1[5];
    float ls0 = 0.f, ls1 = 0.f;
#pragma unroll
    for (int s = 0; s < 5; ++s) {
        u0[s] = exp2f(s0[s] - m0); ls0 += u0[s];
        u1[s] = exp2f(s1[s] - m1); ls1 += u1[s];
    }
    if (lane == 0) { lsum[w][0] = ls0; lsum[w][1] = ls1; }

    // ---- weighted accumulation (unnormalized) ----
    float4 a0a = z4, a0b = z4, a1a = z4, a1b = z4;
#pragma unroll
    for (int s = 0; s < 5; ++s) {
        const float w0 = u0[s], w1 = u1[s];
        a0a.x += w0 * kA[s].x; a0a.y += w0 * kA[s].y; a0a.z += w0 * kA[s].z; a0a.w += w0 * kA[s].w;
        a0b.x += w0 * kB[s].x; a0b.y += w0 * kB[s].y; a0b.z += w0 * kB[s].z; a0b.w += w0 * kB[s].w;
        a1a.x += w1 * kA[s].x; a1a.y += w1 * kA[s].y; a1a.z += w1 * kA[s].z; a1a.w += w1 * kA[s].w;
        a1b.x += w1 * kB[s].x; a1b.y += w1 * kB[s].y; a1b.z += w1 * kB[s].z; a1b.w += w1 * kB[s].w;
    }
    __syncthreads();                                   // B2

    const float r0 = 1.f / (lsum[0][0] + lsum[1][0] + lsum[2][0] + lsum[3][0]);
    const float r1 = 1.f / (lsum[0][1] + lsum[1][1] + lsum[2][1] + lsum[3][1]);

    if (w) {
        accx[w - 1][0][lane] = a0a;
        accx[w - 1][1][lane] = a0b;
        accx[w - 1][2][lane] = a1a;
        accx[w - 1][3][lane] = a1b;
    }
    __syncthreads();                                   // B3

    if (w == 0) {
#pragma unroll
        for (int i = 0; i < 3; ++i) {
            float4 p0a = accx[i][0][lane], p0b = accx[i][1][lane];
            float4 p1a = accx[i][2][lane], p1b = accx[i][3][lane];
            a0a.x += p0a.x; a0a.y += p0a.y; a0a.z += p0a.z; a0a.w += p0a.w;
            a0b.x += p0b.x; a0b.y += p0b.y; a0b.z += p0b.z; a0b.w += p0b.w;
            a1a.x += p1a.x; a1a.y += p1a.y; a1a.z += p1a.z; a1a.w += p1a.w;
            a1b.x += p1b.x; a1b.y += p1b.y; a1b.z += p1b.z; a1b.w += p1b.w;
        }
        const float zf0 = inv ? 0.f : r0;              // wkv zeroed for invalid rows
        const float zf1 = inv ? 0.f : r1;
        float* wrow = wkv + (size_t)b * 888;
        float4 o;
        o.x = a0a.x * zf0; o.y = a0a.y * zf0; o.z = a0a.z * zf0; o.w = a0a.w * zf0;
        *(float4*)(wrow + lane * 4) = o;
        o.x = a1a.x * zf1; o.y = a1a.y * zf1; o.z = a1a.z * zf1; o.w = a1a.w * zf1;
        *(float4*)(wrow + KD + lane * 4) = o;
        if (lane < 47) {
            o.x = a0b.x * zf0; o.y = a0b.y * zf0; o.z = a0b.z * zf0; o.w = a0b.w * zf0;
            *(float4*)(wrow + (64 + lane) * 4) = o;
            o.x = a1b.x * zf1; o.y = a1b.y * zf1; o.z = a1b.z * zf1; o.w = a1b.w * zf1;
            *(float4*)(wrow + KD + (64 + lane) * 4) = o;
        }
        if (lane < NNB)
            attnw[(size_t)b * NNB + lane] =
                0.5f * (exp2f(sc[0][lane] - m0) * r0 + exp2f(sc[1][lane] - m1) * r1);
    }
}

// ---------------------------------------------------------------------------
extern "C" void kernel_launch(void* const* d_in, const int* in_sizes, int n_in,
                              void* d_out, int out_size, void* d_ws, size_t ws_size,
                              hipStream_t stream) {
    const float* src_node = (const float*)d_in[0];
    const float* src_time = (const float*)d_in[1];
    const float* nfp      = (const float*)d_in[2];
    const float* ntfp     = (const float*)d_in[3];  // neighbor_time
    const float* efp      = (const float*)d_in[4];  // edge
    const unsigned char* maskp = (const unsigned char*)d_in[5];
    const float* q_w   = (const float*)d_in[6];
    const float* k_w   = (const float*)d_in[7];
    const float* v_w   = (const float*)d_in[8];
    const float* q_b   = (const float*)d_in[9];
    // d_in[10] = k_b: no effect on outputs (uniform shift under softmax)
    const float* v_b   = (const float*)d_in[11];
    const float* out_w = (const float*)d_in[12];
    const float* out_b = (const float*)d_in[13];
    const float* m1_w  = (const float*)d_in[14];
    const float* m1_b  = (const float*)d_in[15];
    const float* m2_w  = (const float*)d_in[16];
    const float* m2_b  = (const float*)d_in[17];

    const int B = in_sizes[0] / NF;   // 32768

    // ws layout:
    //  flag[16] | qkb [B,888] (qk -> wkv) | invb [B] | hidb [B,172]
    //  | GT[888*272] | gb[888] | mb[272] | OW2[172*272] | W2[172*1060] | bias_v[172]
    float* ws     = (float*)d_ws;
    int*   flag   = (int*)d_ws;
    float* qkb    = ws + 16;
    float* invb   = qkb + (size_t)B * 888;
    float* hidb   = invb + B;
    float* GT     = hidb + (size_t)B * 172;
    float* gb     = GT + 888 * 272;
    float* mb     = gb + 888;
    float* OW2    = mb + 272;
    float* W2     = OW2 + 172 * 272;
    float* bias_v = W2 + 172 * 1060;
    float* outp   = (float*)d_out;                // [B,172]
    float* attnw  = outp + (size_t)B * OUT_D;     // [B,20]

    const int gm = B / 128;   // 256

    sniff_k<<<1, 256, 0, stream>>>(maskp, flag);
    prep1_k<<<1065, 256, 0, stream>>>(q_w, k_w, q_b, v_b, out_w, out_b, m1_w,
                                      GT, gb, OW2, mb);
    prep2_k<<<173, 256, 0, stream>>>(v_w, m1_w, m1_b, OW2, mb, W2, bias_v);

    // GEMM1: qk[B,888] = concat(src_node, src_time) @ GT^T + gb   (K=272)
    gemm_mfma_k<<<dim3(gm, 7), 256, 0, stream>>>(
        src_node, NF, NF, src_time, TF_,
        GT, 272, gb, nullptr, nullptr, 0, qkb, 888, 888, 272);

    // attention (wkv aliases qk; wkv zeroed for invalid rows)
    attn_flash3_k<<<B, 256, 0, stream>>>(nfp, efp, ntfp, maskp, flag,
                                         qkb, qkb, invb, attnw);

    // GEMMf: hidden = relu([wkv | src_node] @ W2^T + bias_sel)   (K=1060)
    gemm_mfma_k<<<dim3(gm, 2), 256, 0, stream>>>(
        qkb, 888, 888, src_node, NF,
        W2, 1060, bias_v, m1_b, invb, 1, hidb, OUT_D, OUT_D, 1060);

    // K8: out = hidden @ m2_w^T + m2_b
    gemm_mfma_k<<<dim3(gm, 2), 256, 0, stream>>>(
        hidb, OUT_D, OUT_D, nullptr, 0,
        m2_w, OUT_D, m2_b, nullptr, nullptr, 0, outp, OUT_D, OUT_D, OUT_D);
}